// Round 14
// baseline (477.923 us; speedup 1.0000x reference)
//
#include <hip/hip_runtime.h>

typedef unsigned short u16;
typedef unsigned int u32;

typedef __attribute__((ext_vector_type(8))) short bf16x8;
typedef __attribute__((ext_vector_type(4))) float f32x4;
typedef __attribute__((ext_vector_type(16))) float f32x16;
typedef __attribute__((ext_vector_type(4))) u32 u32x4;

__device__ __forceinline__ u16 f2bf(float f) {
  u32 u = __builtin_bit_cast(u32, f);
  u32 r = (u + 0x7fffu + ((u >> 16) & 1u)) >> 16;
  return (u16)r;
}
__device__ __forceinline__ float bf2f(u16 h) {
  return __builtin_bit_cast(float, (u32)h << 16);
}
__device__ __forceinline__ u32 cvtpk(float lo, float hi) {
  u32 d;
  asm("v_cvt_pk_bf16_f32 %0, %1, %2" : "=v"(d) : "v"(lo), "v"(hi));
  return d;
}
// v_permlane32_swap_b32: a.hi <-> b.lo.  After: a={a.lo, b.lo}, b={a.hi, b.hi}
__device__ __forceinline__ void plswap(u32& a, u32& b) {
  asm("v_permlane32_swap_b32 %0, %1" : "+v"(a), "+v"(b));
}

#define GLD16(g, l)                                       \
  __builtin_amdgcn_global_load_lds(                       \
      (__attribute__((address_space(1))) void*)(g),       \
      (__attribute__((address_space(3))) void*)(l), 16, 0, 0)

#define WAITV8() asm volatile("s_waitcnt vmcnt(8)" ::: "memory")
#define WAITV0() asm volatile("s_waitcnt vmcnt(0)" ::: "memory")
#define BARF()                               \
  {                                          \
    asm volatile("" ::: "memory");           \
    __builtin_amdgcn_s_barrier();            \
    asm volatile("" ::: "memory");           \
  }

// ---------------- fp32 -> bf16 convert ----------------
__global__ __launch_bounds__(256) void cvt_bf16(const float* __restrict__ src,
                                                u16* __restrict__ dst, int n4) {
  int i = blockIdx.x * 256 + threadIdx.x;
  if (i >= n4) return;
  float4 v = ((const float4*)src)[i];
  ushort4 o;
  o.x = f2bf(v.x); o.y = f2bf(v.y); o.z = f2bf(v.z); o.w = f2bf(v.w);
  ((ushort4*)dst)[i] = o;
}

// ---------------- 4 weight matrices fp32 -> bf16 in one launch ----------------
// each weight: 1048576 float4 -> 4096 blocks of 256 threads; grid 16384 total.
__global__ __launch_bounds__(256) void cvt_w4(const float* __restrict__ s0,
                                              const float* __restrict__ s1,
                                              const float* __restrict__ s2,
                                              const float* __restrict__ s3,
                                              u16* __restrict__ d0,
                                              u16* __restrict__ d1,
                                              u16* __restrict__ d2,
                                              u16* __restrict__ d3) {
  int j = blockIdx.x >> 12;
  int i = (blockIdx.x & 4095) * 256 + threadIdx.x;
  const float* src = (j == 0) ? s0 : (j == 1) ? s1 : (j == 2) ? s2 : s3;
  u16* dst = (j == 0) ? d0 : (j == 1) ? d1 : (j == 2) ? d2 : d3;
  float4 v = ((const float4*)src)[i];
  ushort4 o;
  o.x = f2bf(v.x); o.y = f2bf(v.y); o.z = f2bf(v.z); o.w = f2bf(v.w);
  ((ushort4*)dst)[i] = o;
}

// ---------------- RoPE in place on bf16 Q and K together ----------------
__global__ __launch_bounds__(256) void rope2(u16* __restrict__ qb,
                                             u16* __restrict__ kb,
                                             const float* __restrict__ cosT,
                                             const float* __restrict__ sinT,
                                             float scaleQ) {
  int i = blockIdx.x * 256 + threadIdx.x;  // < B*T*256 = 2097152
  int c4 = (i & 255) << 2;                 // 0..1020
  size_t bt = (size_t)(i >> 8);
  int t = (int)(bt & 2047);
  float4 c1 = *(const float4*)&cosT[(size_t)t * 2048 + c4];
  float4 s1 = *(const float4*)&sinT[(size_t)t * 2048 + c4];
  float4 c2 = *(const float4*)&cosT[(size_t)t * 2048 + c4 + 1024];
  float4 s2 = *(const float4*)&sinT[(size_t)t * 2048 + c4 + 1024];
#pragma unroll
  for (int which = 0; which < 2; which++) {
    u16* buf = which ? kb : qb;
    float scale = which ? 1.0f : scaleQ;
    u16* p1 = buf + bt * 2048 + c4;
    u16* p2 = p1 + 1024;
    ushort4 x1 = *(const ushort4*)p1;
    ushort4 x2 = *(const ushort4*)p2;
    float a0 = bf2f(x1.x), a1 = bf2f(x1.y), a2 = bf2f(x1.z), a3 = bf2f(x1.w);
    float b0 = bf2f(x2.x), b1 = bf2f(x2.y), b2 = bf2f(x2.z), b3 = bf2f(x2.w);
    ushort4 o1, o2;
    o1.x = f2bf((a0 * c1.x - b0 * s1.x) * scale);
    o1.y = f2bf((a1 * c1.y - b1 * s1.y) * scale);
    o1.z = f2bf((a2 * c1.z - b2 * s1.z) * scale);
    o1.w = f2bf((a3 * c1.w - b3 * s1.w) * scale);
    o2.x = f2bf((b0 * c2.x + a0 * s2.x) * scale);
    o2.y = f2bf((b1 * c2.y + a1 * s2.y) * scale);
    o2.z = f2bf((b2 * c2.z + a2 * s2.z) * scale);
    o2.w = f2bf((b3 * c2.w + a3 * s2.w) * scale);
    *(ushort4*)p1 = o1;
    *(ushort4*)p2 = o2;
  }
}

// ======== shared 2-phase 256x256 GEMM core (proven r5/8/10/13) as a macro ====
// Computes acc[8][4] for tile (m0,n0) with A rows m0..m0+255, W rows n0..n0+255.
#define GEMM_CORE(Aptr, Wptr)                                                  \
  __shared__ __attribute__((aligned(16))) char L[131072];                      \
  const int tid = threadIdx.x;                                                 \
  const int lane = tid & 63;                                                   \
  const int w = tid >> 6;                                                      \
  const int wr = w >> 2;                                                       \
  const int wcn = w & 3;                                                       \
  const int r15 = lane & 15, rg = lane >> 4;                                   \
  const int sw = (r15 & 7) << 4;                                               \
  const int trow = tid >> 3;                                                   \
  const int tlog = ((tid & 7) << 4) ^ ((trow & 7) << 4);                       \
  const u16* pA = (Aptr) + (size_t)(m0 + trow) * 2048 + (tlog >> 1);           \
  const u16* pB = (Wptr) + (size_t)(n0 + trow) * 2048 + (tlog >> 1);           \
  char* dA = L + tid * 16;                                                     \
  char* dB = L + 65536 + tid * 16;                                             \
  const char* aBase = L + wr * 16384;                                          \
  const char* bBase = L + 65536 + (wcn >> 1) * 16384 + (wcn & 1) * 8192;       \
  f32x4 acc[8][4] = {};                                                        \
  bf16x8 ar[4][2], br[2][2][2];                                                \
  auto LD_A = [&](int mq, int soff) {                                          \
    _Pragma("unroll") for (int mf = 0; mf < 4; mf++)                           \
        _Pragma("unroll") for (int ks = 0; ks < 2; ks++) {                     \
      int row = mq * 64 + mf * 16 + r15;                                       \
      ar[mf][ks] = *(const bf16x8*)(aBase + soff + row * 128 +                 \
                                    ((ks * 64 + rg * 16) ^ sw));               \
    }                                                                          \
  };                                                                           \
  auto LD_B = [&](int nq, int soff) {                                          \
    _Pragma("unroll") for (int nf = 0; nf < 2; nf++)                           \
        _Pragma("unroll") for (int ks = 0; ks < 2; ks++) {                     \
      int row = nq * 32 + nf * 16 + r15;                                       \
      br[nq][nf][ks] = *(const bf16x8*)(bBase + soff + row * 128 +             \
                                        ((ks * 64 + rg * 16) ^ sw));           \
    }                                                                          \
  };                                                                           \
  auto QUAD = [&](int mq, int nq) {                                            \
    _Pragma("unroll") for (int mf = 0; mf < 4; mf++)                           \
        _Pragma("unroll") for (int nf = 0; nf < 2; nf++)                       \
            _Pragma("unroll") for (int ks = 0; ks < 2; ks++)                   \
        acc[mq * 4 + mf][nq * 2 + nf] =                                        \
            __builtin_amdgcn_mfma_f32_16x16x32_bf16(                           \
                ar[mf][ks], br[nq][nf][ks], acc[mq * 4 + mf][nq * 2 + nf],     \
                0, 0, 0);                                                      \
  };                                                                           \
  auto COMPUTE = [&](int soff) {                                               \
    LD_A(0, soff);                                                             \
    LD_B(0, soff);                                                             \
    LD_B(1, soff);                                                             \
    __builtin_amdgcn_s_setprio(1);                                             \
    QUAD(0, 0);                                                                \
    QUAD(0, 1);                                                                \
    __builtin_amdgcn_s_setprio(0);                                             \
    LD_A(1, soff);                                                             \
    __builtin_amdgcn_s_setprio(1);                                             \
    QUAD(1, 1);                                                                \
    QUAD(1, 0);                                                                \
    __builtin_amdgcn_s_setprio(0);                                             \
  };                                                                           \
  STAGE(dA, pA, 0);                                                            \
  STAGE(dB, pB, 0);                                                            \
  asm volatile("" ::: "memory");                                               \
  STAGE(dA + 32768, pA, 64);                                                   \
  STAGE(dB + 32768, pB, 64);                                                   \
  WAITV8();                                                                    \
  BARF();                                                                      \
  for (int it = 0; it < 16; it++) {                                            \
    COMPUTE(0);                                                                \
    BARF();                                                                    \
    if (it < 15) {                                                             \
      STAGE(dA, pA, (2 * it + 2) * 64);                                        \
      STAGE(dB, pB, (2 * it + 2) * 64);                                        \
      WAITV8();                                                                \
    } else {                                                                   \
      WAITV0();                                                                \
    }                                                                          \
    BARF();                                                                    \
    COMPUTE(32768);                                                            \
    if (it < 15) {                                                             \
      BARF();                                                                  \
      STAGE(dA + 32768, pA, (2 * it + 3) * 64);                                \
      STAGE(dB + 32768, pB, (2 * it + 3) * 64);                                \
      WAITV8();                                                                \
      BARF();                                                                  \
    }                                                                          \
  }

#define STAGE(dst, src, koff)                                   \
  {                                                             \
    _Pragma("unroll")                                           \
    for (int c = 0; c < 4; c++)                                 \
      GLD16((src) + (size_t)c * 131072 + (koff), (dst) + c * 8192); \
  }

// ---------------- fused QKV GEMM: W rows 0..6143 over [Wq;Wk;Wv] ----------------
// grid (24, 32) = 768 blocks. Bijective XCD swizzle: 8 chunks of 96; each XCD
// keeps 4 contiguous M-panels (4MB A) in its private L2.
__global__ __launch_bounds__(512, 2) void gemm_qkv(const u16* __restrict__ A,
                                                   const u16* __restrict__ Wqkv,
                                                   const float* __restrict__ bq,
                                                   const float* __restrict__ bk,
                                                   const float* __restrict__ bv,
                                                   u16* __restrict__ Qb,
                                                   float* __restrict__ k_new,
                                                   u16* __restrict__ Kb,
                                                   float* __restrict__ v_new,
                                                   u16* __restrict__ Vt) {
  const int lin = blockIdx.y * 24 + blockIdx.x;      // 0..767
  const int swz = (lin & 7) * 96 + (lin >> 3);       // bijection
  const int m0 = (swz / 24) * 256, n0 = (swz % 24) * 256;
  GEMM_CORE(A, Wqkv)
  // epilogue: segment by n0>>11 (wave-uniform: 256-col tile within one segment)
  const int seg = n0 >> 11;
  const float* bias = (seg == 0) ? bq : (seg == 1) ? bk : bv;
#pragma unroll
  for (int am = 0; am < 8; am++)
#pragma unroll
    for (int bn = 0; bn < 4; bn++) {
      int n = n0 + wcn * 64 + bn * 16 + r15;
      int nl = n & 2047;
      float bs = bias[nl];
#pragma unroll
      for (int i = 0; i < 4; i++) {
        int m = m0 + wr * 128 + am * 16 + rg * 4 + i;
        float v = acc[am][bn][i] + bs;
        if (seg == 0) {
          Qb[(size_t)m * 2048 + nl] = f2bf(v);
        } else if (seg == 1) {
          k_new[(size_t)m * 2048 + nl] = v;
          Kb[(size_t)m * 2048 + nl] = f2bf(v);
        } else {
          v_new[(size_t)m * 2048 + nl] = v;
          int b_ = m >> 11, t_ = m & 2047, h_ = nl >> 7, d_ = nl & 127;
          Vt[(((size_t)(b_ * 16 + h_) * 128 + d_) << 11) + t_] = f2bf(v);
        }
      }
    }
}

// ---------------- O-projection GEMM (proven r5/8/10/13, verbatim) ----------------
__global__ __launch_bounds__(512, 2) void gemm_bt(const u16* __restrict__ A,
                                                  const u16* __restrict__ Wm,
                                                  const float* __restrict__ bias,
                                                  float* __restrict__ outF) {
  const int lin = blockIdx.y * 8 + blockIdx.x;
  const int swzb = ((lin & 7) << 5) | (lin >> 3);
  const int m0 = (swzb >> 3) * 256, n0 = (swzb & 7) * 256;
  GEMM_CORE(A, Wm)
#pragma unroll
  for (int am = 0; am < 8; am++)
#pragma unroll
    for (int bn = 0; bn < 4; bn++) {
      int n = n0 + wcn * 64 + bn * 16 + r15;
      float bs = bias[n];
#pragma unroll
      for (int i = 0; i < 4; i++) {
        int m = m0 + wr * 128 + am * 16 + rg * 4 + i;
        outF[(size_t)m * 2048 + n] = acc[am][bn][i] + bs;
      }
    }
}
#undef STAGE
#undef GEMM_CORE

// ---------------- causal flash attention: 8-wave + triangular pairing ----------
// grid (4, B*H), 512 threads = 8 waves, each wave owns 32 q rows. KVBLK=64.
// Block p processes q-tile (7-p) then q-tile p (256 rows each) -> uniform 36
// staged KV-tiles/block, 256 blocks = 1/CU. 8-wave compute body proven r9;
// pairing proven r10/r13. K/V dbuf in LDS, 256B rows, 16-slot XOR swizzle.
__global__ __launch_bounds__(512, 2) void attn_fwd(const u16* __restrict__ Qb,
                                                   const u16* __restrict__ Kb,
                                                   const u16* __restrict__ Vt,
                                                   u16* __restrict__ AO) {
  __shared__ __attribute__((aligned(16))) u16 Ks[2][64 * 128];
  __shared__ __attribute__((aligned(16))) u16 Vs[2][64 * 128];
  const int tid = threadIdx.x;
  const int lane = tid & 63;
  const int w = tid >> 6;                    // 0..7
  const int c31 = lane & 31, hi = lane >> 5;
  const int bh = blockIdx.y;
  const int b = bh >> 4, h = bh & 15;
  const int p = blockIdx.x;                  // 0..3 (pair index)

  // staging: 512 threads x 16B = 8KB/chunk -> 2 chunks per 16KB tile
  const u16* ksrc[2];
  const u16* vsrc[2];
  int xoff[2];
#pragma unroll
  for (int c = 0; c < 2; c++) {
    int X = c * 8192 + tid * 16;
    int row = X >> 8, phys = X & 255;
    int lg = phys ^ ((row & 15) << 4);
    xoff[c] = X;
    ksrc[c] = Kb + (size_t)(b * 2048 + row) * 2048 + h * 128 + (lg >> 1);
    int vd = row + ((lg >> 7) << 6);
    int kvb = lg & 127;
    vsrc[c] = Vt + ((size_t)(b * 16 + h) * 128 + vd) * 2048 + (kvb >> 1);
  }

  for (int phase = 0; phase < 2; phase++) {
    const int q0 = (phase == 0 ? (7 - p) : p) * 256;
    const int qw0 = q0 + w * 32;
    const int q = qw0 + c31;                 // this lane's q row

    bf16x8 qreg[8];
    {
      const u16* qp = Qb + ((size_t)(b * 2048 + q)) * 2048 + h * 128 + hi * 8;
#pragma unroll
      for (int ks = 0; ks < 8; ks++) qreg[ks] = *(const bf16x8*)(qp + ks * 16);
    }

    f32x16 accO[4] = {};
    float m_run = -__builtin_inff(), l_run = 0.f;
    const int ntiles = (q0 >> 6) + 4;

    // all waves done reading previous phase's buffers before restaging
    __syncthreads();
#pragma unroll
    for (int c = 0; c < 2; c++) {
      GLD16(ksrc[c], (char*)Ks + xoff[c]);
      GLD16(vsrc[c], (char*)Vs + xoff[c]);
    }

    for (int it = 0; it < ntiles; it++) {
      const int kv0 = it << 6;
      const int buf = it & 1;
      __syncthreads();  // drains staging vmcnt + orders buffers
      if (it + 1 < ntiles) {
        const int nb = buf ^ 1;
        const int kvn = (it + 1) << 6;
#pragma unroll
        for (int c = 0; c < 2; c++) {
          GLD16(ksrc[c] + (size_t)kvn * 2048, (char*)Ks + nb * 16384 + xoff[c]);
          GLD16(vsrc[c] + kvn, (char*)Vs + nb * 16384 + xoff[c]);
        }
      }
      if (kv0 > qw0 + 31) continue;  // wave fully masked (uniform per wave)

      // ---- S^T[64kv x 32q] = K * Q^T
      f32x16 sT[2] = {};
      {
        const char* kb = (const char*)Ks + buf * 16384;
#pragma unroll
        for (int kvt = 0; kvt < 2; kvt++) {
          int krow = kvt * 32 + c31;
          const char* kr = kb + krow * 256;
          int swz = (krow & 15) << 4;
#pragma unroll
          for (int ks = 0; ks < 8; ks++) {
            bf16x8 kf = *(const bf16x8*)(kr + ((ks * 32 + hi * 16) ^ swz));
            sT[kvt] = __builtin_amdgcn_mfma_f32_32x32x16_bf16(kf, qreg[ks], sT[kvt], 0, 0, 0);
          }
        }
      }

      if (kv0 + 63 > qw0) {  // diagonal tile for this wave
#pragma unroll
        for (int kvt = 0; kvt < 2; kvt++)
#pragma unroll
          for (int r = 0; r < 16; r++) {
            int kv = kv0 + kvt * 32 + (r & 3) + 8 * (r >> 2) + 4 * hi;
            if (kv > q) sT[kvt][r] = -__builtin_inff();
          }
      }

      float tm[16];
#pragma unroll
      for (int r = 0; r < 16; r++) tm[r] = fmaxf(sT[0][r], sT[1][r]);
#pragma unroll
      for (int st = 8; st > 0; st >>= 1)
#pragma unroll
        for (int r = 0; r < st; r++) tm[r] = fmaxf(tm[r], tm[r + st]);
      float pmax = tm[0];
      pmax = fmaxf(pmax, __shfl_xor(pmax, 32));

      if (!__all(pmax - m_run <= 8.0f)) {  // defer-max (T13)
        float mnew = fmaxf(m_run, pmax);
        float alpha = exp2f(m_run - mnew);
        m_run = mnew;
        l_run *= alpha;
#pragma unroll
        for (int r = 0; r < 16; r++) {
          float ar = __shfl(alpha, (r & 3) + 8 * (r >> 2) + 4 * hi);
#pragma unroll
          for (int dt = 0; dt < 4; dt++) accO[dt][r] *= ar;
        }
      }

      float a0 = 0.f, a1 = 0.f, a2 = 0.f, a3 = 0.f;
#pragma unroll
      for (int kvt = 0; kvt < 2; kvt++)
#pragma unroll
        for (int r = 0; r < 16; r++) {
          float pv = exp2f(sT[kvt][r] - m_run);
          sT[kvt][r] = pv;
          if ((r & 3) == 0) a0 += pv; else if ((r & 3) == 1) a1 += pv;
          else if ((r & 3) == 2) a2 += pv; else a3 += pv;
        }
      float rs = (a0 + a1) + (a2 + a3);
      rs += __shfl_xor(rs, 32);
      l_run += rs;

      u32x4 pa[4];
#pragma unroll
      for (int kvt = 0; kvt < 2; kvt++)
#pragma unroll
        for (int hf = 0; hf < 2; hf++) {
          u32 wA0 = cvtpk(sT[kvt][hf * 8 + 0], sT[kvt][hf * 8 + 1]);
          u32 wA1 = cvtpk(sT[kvt][hf * 8 + 4], sT[kvt][hf * 8 + 5]);
          u32 wB0 = cvtpk(sT[kvt][hf * 8 + 2], sT[kvt][hf * 8 + 3]);
          u32 wB1 = cvtpk(sT[kvt][hf * 8 + 6], sT[kvt][hf * 8 + 7]);
          plswap(wA0, wA1);
          plswap(wB0, wB1);
          pa[kvt * 2 + hf] = (u32x4){wA0, wB0, wA1, wB1};
        }

      {
        const char* vb = (const char*)Vs + buf * 16384;
#pragma unroll
        for (int dt = 0; dt < 4; dt++) {
          int vrow = (dt & 1) * 32 + c31;
          const char* vr = vb + vrow * 256;
          int swz = (vrow & 15) << 4;
          int hsel = (dt >> 1) * 128;
#pragma unroll
          for (int ks = 0; ks < 4; ks++) {
            bf16x8 vf = *(const bf16x8*)(vr + ((hsel + ks * 32 + hi * 16) ^ swz));
            bf16x8 paf = __builtin_bit_cast(bf16x8, pa[ks]);
            accO[dt] = __builtin_amdgcn_mfma_f32_32x32x16_bf16(paf, vf, accO[dt], 0, 0, 0);
          }
        }
      }
    }

    // epilogue for this phase
    float linv = 1.0f / l_run;
#pragma unroll
    for (int r = 0; r < 16; r++) {
      int crow = (r & 3) + 8 * (r >> 2) + 4 * hi;
      float lr = __shfl(linv, crow);
      int qq = qw0 + crow;
      u16* op = AO + (size_t)(b * 2048 + qq) * 2048 + h * 128 + c31;
#pragma unroll
      for (int dt = 0; dt < 4; dt++) op[dt * 32] = f2bf(accO[dt][r] * lr);
    }
  }
}

extern "C" void kernel_launch(void* const* d_in, const int* in_sizes, int n_in,
                              void* d_out, int out_size, void* d_ws, size_t ws_size,
                              hipStream_t stream) {
  const float* x    = (const float*)d_in[0];
  const float* cosT = (const float*)d_in[1];
  const float* sinT = (const float*)d_in[2];
  const float* Wq   = (const float*)d_in[3];
  const float* bq   = (const float*)d_in[4];
  const float* Wk   = (const float*)d_in[5];
  const float* bk   = (const float*)d_in[6];
  const float* Wv   = (const float*)d_in[7];
  const float* bv   = (const float*)d_in[8];
  const float* Wo   = (const float*)d_in[9];
  const float* bo   = (const float*)d_in[10];

  float* out   = (float*)d_out;
  float* k_new = out + (size_t)16777216;   // B*T*C
  float* v_new = out + (size_t)33554432;

  char* ws = (char*)d_ws;
  u16* xb  = (u16*)(ws);                   // 33.5MB  (reused as AO later)
  u16* Wqb = (u16*)(ws + 33554432);        // 8.4MB each; Wq/Wk/Wv CONTIGUOUS
  u16* Wkb = (u16*)(ws + 41943040);
  u16* Wvb = (u16*)(ws + 50331648);
  u16* Wob = (u16*)(ws + 58720256);
  u16* Qb  = (u16*)(ws + 67108864);        // 33.5MB
  u16* Kb  = (u16*)(ws + 100663296);       // 33.5MB
  u16* Vt  = (u16*)(ws + 134217728);       // 33.5MB  (end: 167772160)
  u16* AO  = xb;

  // fp32 -> bf16 staging
  cvt_bf16<<<16384, 256, 0, stream>>>(x, xb, 4194304);
  cvt_w4<<<16384, 256, 0, stream>>>(Wq, Wk, Wv, Wo, Wqb, Wkb, Wvb, Wob);

  // fused QKV projection (N=6144 over contiguous [Wq;Wk;Wv])
  gemm_qkv<<<dim3(24, 32), 512, 0, stream>>>(xb, Wqb, bq, bk, bv,
                                             Qb, k_new, Kb, v_new, Vt);

  // RoPE on Q (+scale fold) and K in one pass
  const float sc2 = 1.44269504088896f * 0.08838834764831845f;
  rope2<<<8192, 256, 0, stream>>>(Qb, Kb, cosT, sinT, sc2);

  // causal flash attention -> AO (bf16 [B,T,C]), 8-wave paired q-tiles
  attn_fwd<<<dim3(4, 64), 512, 0, stream>>>(Qb, Kb, Vt, AO);

  // output projection
  gemm_bt<<<dim3(8, 32), 512, 0, stream>>>(AO, Wob, bo, out);
}

// Round 15
// 473.034 us; speedup vs baseline: 1.0103x; 1.0103x over previous
//
#include <hip/hip_runtime.h>

typedef unsigned short u16;
typedef unsigned int u32;

typedef __attribute__((ext_vector_type(8))) short bf16x8;
typedef __attribute__((ext_vector_type(4))) float f32x4;
typedef __attribute__((ext_vector_type(16))) float f32x16;
typedef __attribute__((ext_vector_type(4))) u32 u32x4;

__device__ __forceinline__ u16 f2bf(float f) {
  u32 u = __builtin_bit_cast(u32, f);
  u32 r = (u + 0x7fffu + ((u >> 16) & 1u)) >> 16;
  return (u16)r;
}
__device__ __forceinline__ float bf2f(u16 h) {
  return __builtin_bit_cast(float, (u32)h << 16);
}
__device__ __forceinline__ u32 cvtpk(float lo, float hi) {
  u32 d;
  asm("v_cvt_pk_bf16_f32 %0, %1, %2" : "=v"(d) : "v"(lo), "v"(hi));
  return d;
}
// v_permlane32_swap_b32: a.hi <-> b.lo.  After: a={a.lo, b.lo}, b={a.hi, b.hi}
__device__ __forceinline__ void plswap(u32& a, u32& b) {
  asm("v_permlane32_swap_b32 %0, %1" : "+v"(a), "+v"(b));
}

#define GLD16(g, l)                                       \
  __builtin_amdgcn_global_load_lds(                       \
      (__attribute__((address_space(1))) void*)(g),       \
      (__attribute__((address_space(3))) void*)(l), 16, 0, 0)

#define WAITV8() asm volatile("s_waitcnt vmcnt(8)" ::: "memory")
#define WAITV0() asm volatile("s_waitcnt vmcnt(0)" ::: "memory")
#define BARF()                               \
  {                                          \
    asm volatile("" ::: "memory");           \
    __builtin_amdgcn_s_barrier();            \
    asm volatile("" ::: "memory");           \
  }

// ---------------- fp32 -> bf16 convert ----------------
__global__ __launch_bounds__(256) void cvt_bf16(const float* __restrict__ src,
                                                u16* __restrict__ dst, int n4) {
  int i = blockIdx.x * 256 + threadIdx.x;
  if (i >= n4) return;
  float4 v = ((const float4*)src)[i];
  ushort4 o;
  o.x = f2bf(v.x); o.y = f2bf(v.y); o.z = f2bf(v.z); o.w = f2bf(v.w);
  ((ushort4*)dst)[i] = o;
}

// ---------------- 4 weight matrices fp32 -> bf16 in one launch ----------------
// each weight: 1048576 float4 -> 4096 blocks of 256 threads; grid 16384 total.
__global__ __launch_bounds__(256) void cvt_w4(const float* __restrict__ s0,
                                              const float* __restrict__ s1,
                                              const float* __restrict__ s2,
                                              const float* __restrict__ s3,
                                              u16* __restrict__ d0,
                                              u16* __restrict__ d1,
                                              u16* __restrict__ d2,
                                              u16* __restrict__ d3) {
  int j = blockIdx.x >> 12;
  int i = (blockIdx.x & 4095) * 256 + threadIdx.x;
  const float* src = (j == 0) ? s0 : (j == 1) ? s1 : (j == 2) ? s2 : s3;
  u16* dst = (j == 0) ? d0 : (j == 1) ? d1 : (j == 2) ? d2 : d3;
  float4 v = ((const float4*)src)[i];
  ushort4 o;
  o.x = f2bf(v.x); o.y = f2bf(v.y); o.z = f2bf(v.z); o.w = f2bf(v.w);
  ((ushort4*)dst)[i] = o;
}

// ---------------- RoPE in place on bf16 Q and K together ----------------
__global__ __launch_bounds__(256) void rope2(u16* __restrict__ qb,
                                             u16* __restrict__ kb,
                                             const float* __restrict__ cosT,
                                             const float* __restrict__ sinT,
                                             float scaleQ) {
  int i = blockIdx.x * 256 + threadIdx.x;  // < B*T*256 = 2097152
  int c4 = (i & 255) << 2;                 // 0..1020
  size_t bt = (size_t)(i >> 8);
  int t = (int)(bt & 2047);
  float4 c1 = *(const float4*)&cosT[(size_t)t * 2048 + c4];
  float4 s1 = *(const float4*)&sinT[(size_t)t * 2048 + c4];
  float4 c2 = *(const float4*)&cosT[(size_t)t * 2048 + c4 + 1024];
  float4 s2 = *(const float4*)&sinT[(size_t)t * 2048 + c4 + 1024];
#pragma unroll
  for (int which = 0; which < 2; which++) {
    u16* buf = which ? kb : qb;
    float scale = which ? 1.0f : scaleQ;
    u16* p1 = buf + bt * 2048 + c4;
    u16* p2 = p1 + 1024;
    ushort4 x1 = *(const ushort4*)p1;
    ushort4 x2 = *(const ushort4*)p2;
    float a0 = bf2f(x1.x), a1 = bf2f(x1.y), a2 = bf2f(x1.z), a3 = bf2f(x1.w);
    float b0 = bf2f(x2.x), b1 = bf2f(x2.y), b2 = bf2f(x2.z), b3 = bf2f(x2.w);
    ushort4 o1, o2;
    o1.x = f2bf((a0 * c1.x - b0 * s1.x) * scale);
    o1.y = f2bf((a1 * c1.y - b1 * s1.y) * scale);
    o1.z = f2bf((a2 * c1.z - b2 * s1.z) * scale);
    o1.w = f2bf((a3 * c1.w - b3 * s1.w) * scale);
    o2.x = f2bf((b0 * c2.x + a0 * s2.x) * scale);
    o2.y = f2bf((b1 * c2.y + a1 * s2.y) * scale);
    o2.z = f2bf((b2 * c2.z + a2 * s2.z) * scale);
    o2.w = f2bf((b3 * c2.w + a3 * s2.w) * scale);
    *(ushort4*)p1 = o1;
    *(ushort4*)p2 = o2;
  }
}

// ---------------- bf16 GEMM: D[m][n] = sum_k A[m][k]*W[n][k] + bias[n] ----------
// 256x256 tile, BK=64, 8 waves (2M x 4N), per-wave 128x64. LDS 128KB double-buffered.
// Counted vmcnt(8). XCD-aware block swizzle (grid must be 8x32 = 256 blocks).
// (2-phase structure, proven green r5/8/10/13. QKV fusion tried r14: +41us, reverted.)
__global__ __launch_bounds__(512, 2) void gemm_bt(const u16* __restrict__ A,
                                                  const u16* __restrict__ Wm,
                                                  const float* __restrict__ bias,
                                                  float* __restrict__ outF,
                                                  u16* __restrict__ outB,
                                                  u16* __restrict__ outT) {
  // regions (bytes): A slot0 @0, A slot1 @32768, B slot0 @65536, B slot1 @98304
  __shared__ __attribute__((aligned(16))) char L[131072];
  const int tid = threadIdx.x;
  const int lane = tid & 63;
  const int w = tid >> 6;        // 0..7
  const int wr = w >> 2;         // 0..1 : M half
  const int wcn = w & 3;         // 0..3 : N quarter
  const int lin = blockIdx.y * 8 + blockIdx.x;
  const int swz = ((lin & 7) << 5) | (lin >> 3);
  const int m0 = (swz >> 3) * 256, n0 = (swz & 7) * 256;
  const int r15 = lane & 15, rg = lane >> 4;
  const int sw = (r15 & 7) << 4;

  const int trow = tid >> 3;
  const int tlog = ((tid & 7) << 4) ^ ((trow & 7) << 4);
  const u16* pA = A + (size_t)(m0 + trow) * 2048 + (tlog >> 1);
  const u16* pB = Wm + (size_t)(n0 + trow) * 2048 + (tlog >> 1);
  char* dA = L + tid * 16;
  char* dB = L + 65536 + tid * 16;

#define STAGE(dst, src, koff)                                   \
  {                                                             \
    _Pragma("unroll")                                           \
    for (int c = 0; c < 4; c++)                                 \
      GLD16((src) + (size_t)c * 131072 + (koff), (dst) + c * 8192); \
  }

  const char* aBase = L + wr * 16384;
  const char* bBase = L + 65536 + (wcn >> 1) * 16384 + (wcn & 1) * 8192;

  f32x4 acc[8][4] = {};
  bf16x8 ar[4][2], br[2][2][2];

  auto LD_A = [&](int mq, int soff) {
#pragma unroll
    for (int mf = 0; mf < 4; mf++)
#pragma unroll
      for (int ks = 0; ks < 2; ks++) {
        int row = mq * 64 + mf * 16 + r15;
        ar[mf][ks] = *(const bf16x8*)(aBase + soff + row * 128 +
                                      ((ks * 64 + rg * 16) ^ sw));
      }
  };
  auto LD_B = [&](int nq, int soff) {
#pragma unroll
    for (int nf = 0; nf < 2; nf++)
#pragma unroll
      for (int ks = 0; ks < 2; ks++) {
        int row = nq * 32 + nf * 16 + r15;
        br[nq][nf][ks] = *(const bf16x8*)(bBase + soff + row * 128 +
                                          ((ks * 64 + rg * 16) ^ sw));
      }
  };
  auto QUAD = [&](int mq, int nq) {
#pragma unroll
    for (int mf = 0; mf < 4; mf++)
#pragma unroll
      for (int nf = 0; nf < 2; nf++)
#pragma unroll
        for (int ks = 0; ks < 2; ks++)
          acc[mq * 4 + mf][nq * 2 + nf] = __builtin_amdgcn_mfma_f32_16x16x32_bf16(
              ar[mf][ks], br[nq][nf][ks], acc[mq * 4 + mf][nq * 2 + nf], 0, 0, 0);
  };
  auto COMPUTE = [&](int soff) {
    LD_A(0, soff);
    LD_B(0, soff);
    LD_B(1, soff);
    __builtin_amdgcn_s_setprio(1);
    QUAD(0, 0);
    QUAD(0, 1);
    __builtin_amdgcn_s_setprio(0);
    LD_A(1, soff);
    __builtin_amdgcn_s_setprio(1);
    QUAD(1, 1);
    QUAD(1, 0);
    __builtin_amdgcn_s_setprio(0);
  };

  STAGE(dA, pA, 0);
  STAGE(dB, pB, 0);
  asm volatile("" ::: "memory");
  STAGE(dA + 32768, pA, 64);
  STAGE(dB + 32768, pB, 64);
  WAITV8();
  BARF();

  for (int it = 0; it < 16; it++) {
    COMPUTE(0);
    BARF();
    if (it < 15) {
      STAGE(dA, pA, (2 * it + 2) * 64);
      STAGE(dB, pB, (2 * it + 2) * 64);
      WAITV8();
    } else {
      WAITV0();
    }
    BARF();
    COMPUTE(32768);
    if (it < 15) {
      BARF();
      STAGE(dA + 32768, pA, (2 * it + 3) * 64);
      STAGE(dB + 32768, pB, (2 * it + 3) * 64);
      WAITV8();
      BARF();
    }
  }

#pragma unroll
  for (int am = 0; am < 8; am++)
#pragma unroll
    for (int bn = 0; bn < 4; bn++) {
      int n = n0 + wcn * 64 + bn * 16 + r15;
      float bs = bias[n];
#pragma unroll
      for (int i = 0; i < 4; i++) {
        int m = m0 + wr * 128 + am * 16 + rg * 4 + i;
        float v = acc[am][bn][i] + bs;
        if (outF) outF[(size_t)m * 2048 + n] = v;
        if (outB) outB[(size_t)m * 2048 + n] = f2bf(v);
        if (outT) {
          int b_ = m >> 11, t_ = m & 2047, h_ = n >> 7, d_ = n & 127;
          outT[(((size_t)(b_ * 16 + h_) * 128 + d_) << 11) + t_] = f2bf(v);
        }
      }
    }
#undef STAGE
}

// ---------------- causal flash attention: 8-wave + triangular pairing ----------
// (round-14 proven version, verbatim: ~77us)
// grid (4, B*H), 512 threads = 8 waves, each wave owns 32 q rows. KVBLK=64.
// Block p processes q-tile (7-p) then q-tile p (256 rows each) -> uniform 36
// staged KV-tiles/block, 256 blocks = 1/CU.
__global__ __launch_bounds__(512, 2) void attn_fwd(const u16* __restrict__ Qb,
                                                   const u16* __restrict__ Kb,
                                                   const u16* __restrict__ Vt,
                                                   u16* __restrict__ AO) {
  __shared__ __attribute__((aligned(16))) u16 Ks[2][64 * 128];
  __shared__ __attribute__((aligned(16))) u16 Vs[2][64 * 128];
  const int tid = threadIdx.x;
  const int lane = tid & 63;
  const int w = tid >> 6;                    // 0..7
  const int c31 = lane & 31, hi = lane >> 5;
  const int bh = blockIdx.y;
  const int b = bh >> 4, h = bh & 15;
  const int p = blockIdx.x;                  // 0..3 (pair index)

  // staging: 512 threads x 16B = 8KB/chunk -> 2 chunks per 16KB tile
  const u16* ksrc[2];
  const u16* vsrc[2];
  int xoff[2];
#pragma unroll
  for (int c = 0; c < 2; c++) {
    int X = c * 8192 + tid * 16;
    int row = X >> 8, phys = X & 255;
    int lg = phys ^ ((row & 15) << 4);
    xoff[c] = X;
    ksrc[c] = Kb + (size_t)(b * 2048 + row) * 2048 + h * 128 + (lg >> 1);
    int vd = row + ((lg >> 7) << 6);
    int kvb = lg & 127;
    vsrc[c] = Vt + ((size_t)(b * 16 + h) * 128 + vd) * 2048 + (kvb >> 1);
  }

  for (int phase = 0; phase < 2; phase++) {
    const int q0 = (phase == 0 ? (7 - p) : p) * 256;
    const int qw0 = q0 + w * 32;
    const int q = qw0 + c31;                 // this lane's q row

    bf16x8 qreg[8];
    {
      const u16* qp = Qb + ((size_t)(b * 2048 + q)) * 2048 + h * 128 + hi * 8;
#pragma unroll
      for (int ks = 0; ks < 8; ks++) qreg[ks] = *(const bf16x8*)(qp + ks * 16);
    }

    f32x16 accO[4] = {};
    float m_run = -__builtin_inff(), l_run = 0.f;
    const int ntiles = (q0 >> 6) + 4;

    // all waves done reading previous phase's buffers before restaging
    __syncthreads();
#pragma unroll
    for (int c = 0; c < 2; c++) {
      GLD16(ksrc[c], (char*)Ks + xoff[c]);
      GLD16(vsrc[c], (char*)Vs + xoff[c]);
    }

    for (int it = 0; it < ntiles; it++) {
      const int kv0 = it << 6;
      const int buf = it & 1;
      __syncthreads();  // drains staging vmcnt + orders buffers
      if (it + 1 < ntiles) {
        const int nb = buf ^ 1;
        const int kvn = (it + 1) << 6;
#pragma unroll
        for (int c = 0; c < 2; c++) {
          GLD16(ksrc[c] + (size_t)kvn * 2048, (char*)Ks + nb * 16384 + xoff[c]);
          GLD16(vsrc[c] + kvn, (char*)Vs + nb * 16384 + xoff[c]);
        }
      }
      if (kv0 > qw0 + 31) continue;  // wave fully masked (uniform per wave)

      // ---- S^T[64kv x 32q] = K * Q^T
      f32x16 sT[2] = {};
      {
        const char* kb = (const char*)Ks + buf * 16384;
#pragma unroll
        for (int kvt = 0; kvt < 2; kvt++) {
          int krow = kvt * 32 + c31;
          const char* kr = kb + krow * 256;
          int swz = (krow & 15) << 4;
#pragma unroll
          for (int ks = 0; ks < 8; ks++) {
            bf16x8 kf = *(const bf16x8*)(kr + ((ks * 32 + hi * 16) ^ swz));
            sT[kvt] = __builtin_amdgcn_mfma_f32_32x32x16_bf16(kf, qreg[ks], sT[kvt], 0, 0, 0);
          }
        }
      }

      if (kv0 + 63 > qw0) {  // diagonal tile for this wave
#pragma unroll
        for (int kvt = 0; kvt < 2; kvt++)
#pragma unroll
          for (int r = 0; r < 16; r++) {
            int kv = kv0 + kvt * 32 + (r & 3) + 8 * (r >> 2) + 4 * hi;
            if (kv > q) sT[kvt][r] = -__builtin_inff();
          }
      }

      float tm[16];
#pragma unroll
      for (int r = 0; r < 16; r++) tm[r] = fmaxf(sT[0][r], sT[1][r]);
#pragma unroll
      for (int st = 8; st > 0; st >>= 1)
#pragma unroll
        for (int r = 0; r < st; r++) tm[r] = fmaxf(tm[r], tm[r + st]);
      float pmax = tm[0];
      pmax = fmaxf(pmax, __shfl_xor(pmax, 32));

      if (!__all(pmax - m_run <= 8.0f)) {  // defer-max (T13)
        float mnew = fmaxf(m_run, pmax);
        float alpha = exp2f(m_run - mnew);
        m_run = mnew;
        l_run *= alpha;
#pragma unroll
        for (int r = 0; r < 16; r++) {
          float ar = __shfl(alpha, (r & 3) + 8 * (r >> 2) + 4 * hi);
#pragma unroll
          for (int dt = 0; dt < 4; dt++) accO[dt][r] *= ar;
        }
      }

      float a0 = 0.f, a1 = 0.f, a2 = 0.f, a3 = 0.f;
#pragma unroll
      for (int kvt = 0; kvt < 2; kvt++)
#pragma unroll
        for (int r = 0; r < 16; r++) {
          float pv = exp2f(sT[kvt][r] - m_run);
          sT[kvt][r] = pv;
          if ((r & 3) == 0) a0 += pv; else if ((r & 3) == 1) a1 += pv;
          else if ((r & 3) == 2) a2 += pv; else a3 += pv;
        }
      float rs = (a0 + a1) + (a2 + a3);
      rs += __shfl_xor(rs, 32);
      l_run += rs;

      u32x4 pa[4];
#pragma unroll
      for (int kvt = 0; kvt < 2; kvt++)
#pragma unroll
        for (int hf = 0; hf < 2; hf++) {
          u32 wA0 = cvtpk(sT[kvt][hf * 8 + 0], sT[kvt][hf * 8 + 1]);
          u32 wA1 = cvtpk(sT[kvt][hf * 8 + 4], sT[kvt][hf * 8 + 5]);
          u32 wB0 = cvtpk(sT[kvt][hf * 8 + 2], sT[kvt][hf * 8 + 3]);
          u32 wB1 = cvtpk(sT[kvt][hf * 8 + 6], sT[kvt][hf * 8 + 7]);
          plswap(wA0, wA1);
          plswap(wB0, wB1);
          pa[kvt * 2 + hf] = (u32x4){wA0, wB0, wA1, wB1};
        }

      {
        const char* vb = (const char*)Vs + buf * 16384;
#pragma unroll
        for (int dt = 0; dt < 4; dt++) {
          int vrow = (dt & 1) * 32 + c31;
          const char* vr = vb + vrow * 256;
          int swz = (vrow & 15) << 4;
          int hsel = (dt >> 1) * 128;
#pragma unroll
          for (int ks = 0; ks < 4; ks++) {
            bf16x8 vf = *(const bf16x8*)(vr + ((hsel + ks * 32 + hi * 16) ^ swz));
            bf16x8 paf = __builtin_bit_cast(bf16x8, pa[ks]);
            accO[dt] = __builtin_amdgcn_mfma_f32_32x32x16_bf16(paf, vf, accO[dt], 0, 0, 0);
          }
        }
      }
    }

    // epilogue for this phase
    float linv = 1.0f / l_run;
#pragma unroll
    for (int r = 0; r < 16; r++) {
      int crow = (r & 3) + 8 * (r >> 2) + 4 * hi;
      float lr = __shfl(linv, crow);
      int qq = qw0 + crow;
      u16* op = AO + (size_t)(b * 2048 + qq) * 2048 + h * 128 + c31;
#pragma unroll
      for (int dt = 0; dt < 4; dt++) op[dt * 32] = f2bf(accO[dt][r] * lr);
    }
  }
}

extern "C" void kernel_launch(void* const* d_in, const int* in_sizes, int n_in,
                              void* d_out, int out_size, void* d_ws, size_t ws_size,
                              hipStream_t stream) {
  const float* x    = (const float*)d_in[0];
  const float* cosT = (const float*)d_in[1];
  const float* sinT = (const float*)d_in[2];
  const float* Wq   = (const float*)d_in[3];
  const float* bq   = (const float*)d_in[4];
  const float* Wk   = (const float*)d_in[5];
  const float* bk   = (const float*)d_in[6];
  const float* Wv   = (const float*)d_in[7];
  const float* bv   = (const float*)d_in[8];
  const float* Wo   = (const float*)d_in[9];
  const float* bo   = (const float*)d_in[10];

  float* out   = (float*)d_out;
  float* k_new = out + (size_t)16777216;   // B*T*C
  float* v_new = out + (size_t)33554432;

  char* ws = (char*)d_ws;
  u16* xb  = (u16*)(ws);                   // 33.5MB  (reused as AO later)
  u16* Wqb = (u16*)(ws + 33554432);        // 8.4MB each
  u16* Wkb = (u16*)(ws + 41943040);
  u16* Wvb = (u16*)(ws + 50331648);
  u16* Wob = (u16*)(ws + 58720256);
  u16* Qb  = (u16*)(ws + 67108864);        // 33.5MB
  u16* Kb  = (u16*)(ws + 100663296);       // 33.5MB
  u16* Vt  = (u16*)(ws + 134217728);       // 33.5MB  (end: 167772160)
  u16* AO  = xb;

  // fp32 -> bf16 staging
  cvt_bf16<<<16384, 256, 0, stream>>>(x, xb, 4194304);
  cvt_w4<<<16384, 256, 0, stream>>>(Wq, Wk, Wv, Wo, Wqb, Wkb, Wvb, Wob);

  // projections (256x256 tile, 512 threads, 2-phase proven; separate launches)
  dim3 gg(8, 32);
  gemm_bt<<<gg, 512, 0, stream>>>(xb, Wqb, bq, nullptr, Qb, nullptr);
  gemm_bt<<<gg, 512, 0, stream>>>(xb, Wkb, bk, k_new, Kb, nullptr);
  gemm_bt<<<gg, 512, 0, stream>>>(xb, Wvb, bv, v_new, nullptr, Vt);

  // RoPE on Q (+scale fold) and K in one pass
  const float sc2 = 1.44269504088896f * 0.08838834764831845f;
  rope2<<<8192, 256, 0, stream>>>(Qb, Kb, cosT, sinT, sc2);

  // causal flash attention -> AO (bf16 [B,T,C]), 8-wave paired q-tiles
  attn_fwd<<<dim3(4, 64), 512, 0, stream>>>(Qb, Kb, Vt, AO);

  // output projection
  gemm_bt<<<gg, 512, 0, stream>>>(AO, Wob, bo, out, nullptr, nullptr);
}